// Round 22
// baseline (88.857 us; speedup 1.0000x reference)
//
#include <hip/hip_runtime.h>

// GCN forward: algebraic collapse + split-bf16 MFMA GEMM (4 products) + bucket
// scatter + LDS-atomic bucket aggregation (NO sort, NO csr — R21).
//   k_prep : Wf split (hi) + E1/E2 tables + u/v + zero(cur)
//   k_main : [0,Gg) merged main+mask GEMM ; [Gg,Gg+NB) edge bucket-scatter
//   k_dis  : per-bucket degree histogram -> dq = rsqrt(deg+1), Tq = dq * P
//   k_agg1 : per-bucket edge-parallel: acc[d] += Tq[s] (LDS f32 atomics);
//            T2[n] = d*(d*(Tq[n]+acc) + u)
//   k_agg2 : same on T2; out[n] = (d*(T2[n]+acc) + v) * Pm[n]
// Math:  Z = Â(Â(X1@Wbig) + 1⊗u) + 1⊗v,  Â = D^-1/2 (A+I) D^-1/2
//        out = Z * (lrelu((F-MF)@W_in+b_in)@W_out + b_out)
// Compiler law (R13-R17): VGPR cap ~= 256/w for launch_bounds(256,w); missing
// bounds caps at 64. GEMM stays at (256,2).

#define NEG_SLOPE 0.01f
constexpr int HD = 256;
constexpr int CHUNK = 4096;   // edges per scatter block (196 blocks)
constexpr int BSTRIDE = 8192; // packed bucket capacity (expected ~4082)

typedef __bf16 bf16x8 __attribute__((ext_vector_type(8)));
typedef unsigned short u16x8 __attribute__((ext_vector_type(8)));
typedef float f32x4 __attribute__((ext_vector_type(4)));

#define MFMA16 __builtin_amdgcn_mfma_f32_16x16x32_bf16

// split fp32 -> bf16 hi (truncate) + bf16 lo (RNE of remainder)
__device__ inline void split1(float v, unsigned short& h, unsigned short& l) {
  unsigned u = __float_as_uint(v);
  unsigned hb = u & 0xFFFF0000u;
  float lf = v - __uint_as_float(hb);
  unsigned ul = __float_as_uint(lf);
  h = (unsigned short)(hb >> 16);
  l = (unsigned short)((ul + 0x7FFFu + ((ul >> 16) & 1u)) >> 16);
}

// bf16 RNE of fp32
__device__ inline unsigned short bf16rne(float v) {
  unsigned u = __float_as_uint(v);
  return (unsigned short)((u + 0x7FFFu + ((u >> 16) & 1u)) >> 16);
}

// ---------------- prep: W-split (hi) + consts + E1/E2 tables + zero(cur) --------
__global__ __launch_bounds__(256) void k_prep(
    const float* __restrict__ Win, u16x8* __restrict__ Wf,
    const float* __restrict__ Wg1, const float* __restrict__ Wg2,
    const float* __restrict__ Wo, const float* __restrict__ bin,
    const float* __restrict__ bg1, const float* __restrict__ bg2,
    const float* __restrict__ bo, float4* __restrict__ E1,
    float2* __restrict__ E2, float* __restrict__ uv, int* __restrict__ cur) {
  __shared__ float wt[256][2];
  const int bid = blockIdx.x, tid = threadIdx.x;
  if (bid < 16) {
    // fragment f = nt*4 + ks (hi only); lane's 8 elems:
    //   Win[ks*32 + (lane>>4)*8 + j][nt*16 + (lane&15)]
    int f = bid * 4 + (tid >> 6);
    int lane = tid & 63;
    int nt = f >> 2, ks = f & 3;
    int n = nt * 16 + (lane & 15);
    int k0 = ks * 32 + (lane >> 4) * 8;
    u16x8 outv;
    #pragma unroll
    for (int j = 0; j < 8; ++j)
      outv[j] = bf16rne(Win[(size_t)(k0 + j) * HD + n]);
    Wf[f * 64 + lane] = outv;
  } else if (bid == 16) {
    int r = tid;
    float s0 = 0.f, s1 = 0.f;
    for (int k = 0; k < 256; ++k) {
      float w = Wg2[r * 256 + k];
      s0 = fmaf(w, Wo[k * 2 + 0], s0);
      s1 = fmaf(w, Wo[k * 2 + 1], s1);
    }
    wt[r][0] = s0; wt[r][1] = s1;
    __syncthreads();
    float b0 = 0.f, b1 = 0.f;
    for (int k = 0; k < 256; ++k) {
      float w = Wg1[r * 256 + k];
      b0 = fmaf(w, wt[k][0], b0);
      b1 = fmaf(w, wt[k][1], b1);
    }
    E1[r] = make_float4(bin[r], b0, b1, 0.f);          // {bias, wbig0, wbig1}
    E2[r] = make_float2(Wo[r * 2 + 0], Wo[r * 2 + 1]); // {wo0, wo1}
    if (r < 2) {
      float u = 0.f, v = 0.f;
      for (int k = 0; k < 256; ++k) {
        u = fmaf(bg1[k], wt[k][r], u);
        v = fmaf(bg2[k], Wo[k * 2 + r], v);
      }
      uv[r] = u;             // u[c]
      uv[2 + r] = v + bo[r]; // v[c]
    }
  } else {
    cur[tid] = 0;
  }
}

// ---------------- main: GEMM role [0,Gg) + edge-scatter role [Gg,Gg+NB) ---------
__global__ __launch_bounds__(256, 2) void k_main(
    const float* __restrict__ mf, const float* __restrict__ fe,
    const u16x8* __restrict__ Wf, const float4* __restrict__ E1,
    const float2* __restrict__ E2, const float* __restrict__ bo,
    float2* __restrict__ P, float2* __restrict__ Pm,
    const int* __restrict__ src, const int* __restrict__ dst,
    int* __restrict__ cur, unsigned* __restrict__ packed,
    int N, int E, int Gg) {
  __shared__ __align__(16) char smem[20608];
  const int tid = threadIdx.x;
  const int lane = tid & 63, wid = tid >> 6;

  if ((int)blockIdx.x < Gg) {
    // ---- GEMM role: 4 waves x 16 rows = 64 rows/block ----
    float4* sE1 = (float4*)smem;           // 4 KB
    float2* sE2 = (float2*)(smem + 4096);  // 2 KB
    sE1[tid] = E1[tid];
    sE2[tid] = E2[tid];

    const int gb = blockIdx.x * 64;
    const int base = gb + wid * 16;
    int arow = base + (lane & 15);
    if (arow >= N) arow = N - 1;
    const int kb = (lane >> 4) * 8;
    const float* ap = mf + (size_t)arow * 128 + kb;
    const float* fp = fe + (size_t)arow * 128 + kb;

    // A fragments in regs: main = MF (hi/lo), mask = FE - MF (hi/lo)
    bf16x8 Ah[4], Al[4], Kh[4], Kl[4];
    #pragma unroll
    for (int ks = 0; ks < 4; ++ks) {
      float x[8], y[8];
      *(float4*)&x[0] = *(const float4*)(ap + ks * 32);
      *(float4*)&x[4] = *(const float4*)(ap + ks * 32 + 4);
      *(float4*)&y[0] = *(const float4*)(fp + ks * 32);
      *(float4*)&y[4] = *(const float4*)(fp + ks * 32 + 4);
      u16x8 hA, lA, hM, lM;
      #pragma unroll
      for (int j = 0; j < 8; ++j) {
        unsigned short hh, ll;
        split1(x[j], hh, ll);        hA[j] = hh; lA[j] = ll;
        split1(y[j] - x[j], hh, ll); hM[j] = hh; lM[j] = ll;
      }
      Ah[ks] = __builtin_bit_cast(bf16x8, hA);
      Al[ks] = __builtin_bit_cast(bf16x8, lA);
      Kh[ks] = __builtin_bit_cast(bf16x8, hM);
      Kl[ks] = __builtin_bit_cast(bf16x8, lM);
    }
    __syncthreads(); // sE1/sE2 ready

    const u16x8* wp = Wf + lane; // fragment stride = 64 lanes; 4 frags per nt
    float s0[4] = {}, s1[4] = {}, t0v[4] = {}, t1v[4] = {};
    u16x8 bA[4], bB[4];
    #pragma unroll
    for (int f = 0; f < 4; ++f) bA[f] = wp[f * 64]; // nt=0

    // 4 independent accumulator chains; B = hi only
    auto COMPUTE = [&](const u16x8* b, int nt) {
      f32x4 a0 = {0,0,0,0}, a1 = {0,0,0,0};
      f32x4 k0 = {0,0,0,0}, k1 = {0,0,0,0};
      #pragma unroll
      for (int ks = 0; ks < 4; ++ks) {
        bf16x8 bh = __builtin_bit_cast(bf16x8, b[ks]);
        a0 = MFMA16(Ah[ks], bh, a0, 0, 0, 0);
        a1 = MFMA16(Al[ks], bh, a1, 0, 0, 0);
        k0 = MFMA16(Kh[ks], bh, k0, 0, 0, 0);
        k1 = MFMA16(Kl[ks], bh, k1, 0, 0, 0);
      }
      const int col = nt * 16 + (lane & 15);
      const float4 e1 = sE1[col];
      const float2 e2 = sE2[col];
      #pragma unroll
      for (int r = 0; r < 4; ++r) {
        float a = (a0[r] + a1[r]) + e1.x;
        a = a > 0.f ? a : NEG_SLOPE * a;
        s0[r] = fmaf(a, e1.y, s0[r]); s1[r] = fmaf(a, e1.z, s1[r]);
        float m = (k0[r] + k1[r]) + e1.x;
        m = m > 0.f ? m : NEG_SLOPE * m;
        t0v[r] = fmaf(m, e2.x, t0v[r]); t1v[r] = fmaf(m, e2.y, t1v[r]);
      }
    };

    #pragma unroll 1
    for (int nt = 0; nt < 16; nt += 2) {
      #pragma unroll
      for (int f = 0; f < 4; ++f) bB[f] = wp[((nt + 1) * 4 + f) * 64];
      COMPUTE(bA, nt);
      if (nt + 2 < 16) {
        #pragma unroll
        for (int f = 0; f < 4; ++f) bA[f] = wp[((nt + 2) * 4 + f) * 64];
      }
      COMPUTE(bB, nt + 1);
    }

    #pragma unroll
    for (int o = 1; o < 16; o <<= 1) {
      #pragma unroll
      for (int r = 0; r < 4; ++r) {
        s0[r] += __shfl_xor(s0[r], o, 16);  s1[r] += __shfl_xor(s1[r], o, 16);
        t0v[r] += __shfl_xor(t0v[r], o, 16); t1v[r] += __shfl_xor(t1v[r], o, 16);
      }
    }
    if ((lane & 15) == 0) {
      float bo0 = bo[0], bo1 = bo[1];
      #pragma unroll
      for (int r = 0; r < 4; ++r) {
        int row = base + (lane >> 4) * 4 + r;
        if (row < N) {
          P[row]  = make_float2(s0[r], s1[r]);            // unscaled logits
          Pm[row] = make_float2(t0v[r] + bo0, t1v[r] + bo1); // mask + b_out
        }
      }
    }
    return;
  }

  // ---- scatter role: LDS hist+sort, coalesced per-bin global writes ----
  int* bins   = (int*)smem;              // 1 KB
  int* lstart = (int*)(smem + 1024);     // 1 KB
  int* gbase  = (int*)(smem + 2048);     // 1 KB
  int* lcur   = (int*)(smem + 3072);     // 1 KB
  int* wsum   = (int*)(smem + 4096);     // 16 B
  unsigned* sbuf = (unsigned*)(smem + 4112); // 16 KB
  const int t = tid, b = blockIdx.x - Gg;
  bins[t] = 0;
  __syncthreads();
  const int e0 = b * CHUNK, e1 = min(e0 + CHUNK, E), m = e1 - e0;
  for (int e = e0 + t; e < e1; e += 256)
    atomicAdd(&bins[dst[e] >> 8], 1);
  __syncthreads();
  {
    int v = bins[t], incl = v;
    #pragma unroll
    for (int o = 1; o < 64; o <<= 1) {
      int tmp = __shfl_up(incl, o, 64);
      if (lane >= o) incl += tmp;
    }
    if (lane == 63) wsum[wid] = incl;
    __syncthreads();
    int woff = 0;
    for (int w = 0; w < wid; ++w) woff += wsum[w];
    int st = woff + incl - v;
    lstart[t] = st;
    lcur[t] = st;
    gbase[t] = v ? atomicAdd(&cur[t], v) : 0;
  }
  __syncthreads();
  for (int e = e0 + t; e < e1; e += 256) {
    int d = dst[e], s = src[e];
    int slot = atomicAdd(&lcur[d >> 8], 1);
    sbuf[slot] = ((unsigned)d << 16) | (unsigned)s;
  }
  __syncthreads();
  for (int i = t; i < m; i += 256) {
    unsigned pv = sbuf[i];
    int bin = pv >> 24;
    packed[(size_t)bin * BSTRIDE + gbase[bin] + (i - lstart[bin])] = pv;
  }
}

// ---------------- dis: per-bucket degree -> dq, Tq = dq * P ----------------
__global__ __launch_bounds__(1024) void k_dis(
    const unsigned* __restrict__ packed, const int* __restrict__ cur,
    const float2* __restrict__ P, float* __restrict__ dq,
    float2* __restrict__ Tq, int N) {
  __shared__ int cnt[256];
  const int tid = threadIdx.x, B = blockIdx.x;
  if (tid < 256) cnt[tid] = 0;
  __syncthreads();
  const int ecnt = cur[B];
  const unsigned* pk = packed + (size_t)B * BSTRIDE;
  for (int i = tid; i < ecnt; i += 1024)
    atomicAdd(&cnt[(pk[i] >> 16) & 0xFF], 1);
  __syncthreads();
  if (tid < 256) {
    int node = B * 256 + tid;
    if (node < N) {
      float d = rsqrtf((float)(cnt[tid] + 1)); // +1 self-loop
      dq[node] = d;
      float2 p = P[node];
      Tq[node] = make_float2(d * p.x, d * p.y);
    }
  }
}

// ---------------- agg1: acc[d] += Tq[s]; T2[n] = d*(d*(Tq[n]+acc)+u) ------------
__global__ __launch_bounds__(1024) void k_agg1(
    const unsigned* __restrict__ packed, const int* __restrict__ cur,
    const float2* __restrict__ Tq, const float* __restrict__ dq,
    const float* __restrict__ uv, float2* __restrict__ T2, int N) {
  __shared__ float acc[512];
  const int tid = threadIdx.x, B = blockIdx.x;
  if (tid < 512) acc[tid] = 0.f;
  __syncthreads();
  const int ecnt = cur[B];
  const unsigned* pk = packed + (size_t)B * BSTRIDE;
  int i = tid;
  for (; i + 1024 < ecnt; i += 2048) {
    unsigned p0 = pk[i], p1 = pk[i + 1024];
    float2 t0 = Tq[p0 & 0xFFFFu];
    float2 t1 = Tq[p1 & 0xFFFFu];
    int d0 = ((p0 >> 16) & 0xFF) * 2, d1 = ((p1 >> 16) & 0xFF) * 2;
    atomicAdd(&acc[d0], t0.x); atomicAdd(&acc[d0 + 1], t0.y);
    atomicAdd(&acc[d1], t1.x); atomicAdd(&acc[d1 + 1], t1.y);
  }
  if (i < ecnt) {
    unsigned p0 = pk[i];
    float2 t0 = Tq[p0 & 0xFFFFu];
    int d0 = ((p0 >> 16) & 0xFF) * 2;
    atomicAdd(&acc[d0], t0.x); atomicAdd(&acc[d0 + 1], t0.y);
  }
  __syncthreads();
  if (tid < 256) {
    int node = B * 256 + tid;
    if (node < N) {
      float d = dq[node];
      float2 tn = Tq[node];
      T2[node] = make_float2(d * (d * (tn.x + acc[tid * 2 + 0]) + uv[0]),
                             d * (d * (tn.y + acc[tid * 2 + 1]) + uv[1]));
    }
  }
}

// ---------------- agg2: acc[d] += T2[s]; out[n] = (d*(T2[n]+acc)+v)*Pm[n] -------
__global__ __launch_bounds__(1024) void k_agg2(
    const unsigned* __restrict__ packed, const int* __restrict__ cur,
    const float2* __restrict__ T2, const float* __restrict__ dq,
    const float* __restrict__ uv, const float2* __restrict__ Pm,
    float2* __restrict__ out, int N) {
  __shared__ float acc[512];
  const int tid = threadIdx.x, B = blockIdx.x;
  if (tid < 512) acc[tid] = 0.f;
  __syncthreads();
  const int ecnt = cur[B];
  const unsigned* pk = packed + (size_t)B * BSTRIDE;
  int i = tid;
  for (; i + 1024 < ecnt; i += 2048) {
    unsigned p0 = pk[i], p1 = pk[i + 1024];
    float2 t0 = T2[p0 & 0xFFFFu];
    float2 t1 = T2[p1 & 0xFFFFu];
    int d0 = ((p0 >> 16) & 0xFF) * 2, d1 = ((p1 >> 16) & 0xFF) * 2;
    atomicAdd(&acc[d0], t0.x); atomicAdd(&acc[d0 + 1], t0.y);
    atomicAdd(&acc[d1], t1.x); atomicAdd(&acc[d1 + 1], t1.y);
  }
  if (i < ecnt) {
    unsigned p0 = pk[i];
    float2 t0 = T2[p0 & 0xFFFFu];
    int d0 = ((p0 >> 16) & 0xFF) * 2;
    atomicAdd(&acc[d0], t0.x); atomicAdd(&acc[d0 + 1], t0.y);
  }
  __syncthreads();
  if (tid < 256) {
    int node = B * 256 + tid;
    if (node < N) {
      float d = dq[node];
      float2 tn = T2[node];
      float2 pm = Pm[node];
      float z0 = d * (tn.x + acc[tid * 2 + 0]) + uv[2];
      float z1 = d * (tn.y + acc[tid * 2 + 1]) + uv[3];
      out[node] = make_float2(z0 * pm.x, z1 * pm.y);
    }
  }
}

extern "C" void kernel_launch(void* const* d_in, const int* in_sizes, int n_in,
                              void* d_out, int out_size, void* d_ws, size_t ws_size,
                              hipStream_t stream) {
  const float* mf  = (const float*)d_in[0];
  const float* fe  = (const float*)d_in[1];
  const int*   ei  = (const int*)d_in[2];
  const float* Win = (const float*)d_in[4];
  const float* bin = (const float*)d_in[5];
  const float* Wg1 = (const float*)d_in[6];
  const float* bg1 = (const float*)d_in[7];
  const float* Wg2 = (const float*)d_in[8];
  const float* bg2 = (const float*)d_in[9];
  const float* Wo  = (const float*)d_in[10];
  const float* bo  = (const float*)d_in[11];
  float2* out = (float2*)d_out;

  const int ED = 128;
  const int N = in_sizes[0] / ED;  // 50000
  const int E = in_sizes[3];       // 800000
  const int* src = ei;
  const int* dst = ei + E;

  char* ws = (char*)d_ws;
  size_t off = 0;
  auto carve = [&](size_t bytes) {
    char* p = ws + off;
    off += (bytes + 255) & ~(size_t)255;
    return p;
  };
  int*      cur    = (int*)carve(256 * 4);
  unsigned* packed = (unsigned*)carve((size_t)256 * BSTRIDE * 4); // 8 MB
  float2*   P      = (float2*)carve((size_t)N * 8);
  float*    dq     = (float*)carve((size_t)N * 4);
  float2*   Tq     = (float2*)carve((size_t)N * 8);
  float2*   T2     = (float2*)carve((size_t)N * 8);
  float2*   Pm     = (float2*)carve((size_t)N * 8);
  float4*   E1     = (float4*)carve((size_t)HD * 16);  // {bias, wbig0, wbig1, -}
  float2*   E2     = (float2*)carve((size_t)HD * 8);   // {wo0, wo1}
  float*    uv     = (float*)carve(4 * 4);
  u16x8*    Wf     = (u16x8*)carve((size_t)64 * 64 * 16); // 64 KB (hi only)
  (void)ws_size; (void)n_in; (void)out_size;

  const int NB  = (E + CHUNK - 1) / CHUNK;  // 196 scatter role blocks
  const int NP2 = (N + 255) / 256;          // 196 buckets
  const int Gg  = (N + 63) / 64;            // 782 GEMM role blocks

  k_prep<<<18, 256, 0, stream>>>(Win, Wf, Wg1, Wg2, Wo, bin, bg1, bg2, bo,
                                 E1, E2, uv, cur);
  k_main<<<Gg + NB, 256, 0, stream>>>(mf, fe, Wf, E1, E2, bo, P, Pm,
                                      src, dst, cur, packed, N, E, Gg);
  k_dis<<<NP2, 1024, 0, stream>>>(packed, cur, P, dq, Tq, N);
  k_agg1<<<NP2, 1024, 0, stream>>>(packed, cur, Tq, dq, uv, T2, N);
  k_agg2<<<NP2, 1024, 0, stream>>>(packed, cur, T2, dq, uv, Pm, out, N);
}

// Round 23
// 82.433 us; speedup vs baseline: 1.0779x; 1.0779x over previous
//
#include <hip/hip_runtime.h>

// GCN forward: algebraic collapse + split-bf16 MFMA GEMM (4 products).
// FINAL (R22 = R19, the measured best: 82.87us). Pipeline:
//   k_prep  : Wf split (hi) + E1/E2 tables + u/v + zero(cur)
//   k_main  : [0,Gg) merged main+mask GEMM ; [Gg,Gg+NB) edge bucket-scatter
//   k_p2    : per-bucket sort -> rp/dis/csr
//   k_gather1 / k_gather2 : two Â applications on [N,2] data (8 lanes/node)
// Math:  Z = Â(Â(X1@Wbig) + 1⊗u) + 1⊗v,  Â = D^-1/2 (A+I) D^-1/2
//        out = Z * (lrelu((F-MF)@W_in+b_in)@W_out + b_out)
// Session log: 678us fp32 naive -> 82.9us via (1) linear-algebra collapse of all
// post-lrelu layers into [256,2] (kills 2 GEMMs + [N,256] aggregations), (2)
// bucket-sort CSR (no global fp32 atomics), (3) split-bf16 MFMA with W-residual
// dropped (error budget 5x margin), (4) scatter//GEMM role-block overlap.
// Falsified levers (R6-R21): B-path restructures x4, A-coalescing, occupancy
// 2->8 waves/SIMD, 6-chain ILP, LDS-atomic agg. Compiler law: VGPR cap ~=
// 256/w for launch_bounds(256,w); w>=3 or missing bounds -> spill (>110 live).

#define NEG_SLOPE 0.01f
constexpr int HD = 256;
constexpr int CHUNK = 4096;   // edges per scatter block (196 blocks)
constexpr int BSTRIDE = 8192; // packed bucket capacity (expected ~4082)

typedef __bf16 bf16x8 __attribute__((ext_vector_type(8)));
typedef unsigned short u16x8 __attribute__((ext_vector_type(8)));
typedef float f32x4 __attribute__((ext_vector_type(4)));

#define MFMA16 __builtin_amdgcn_mfma_f32_16x16x32_bf16

// split fp32 -> bf16 hi (truncate) + bf16 lo (RNE of remainder)
__device__ inline void split1(float v, unsigned short& h, unsigned short& l) {
  unsigned u = __float_as_uint(v);
  unsigned hb = u & 0xFFFF0000u;
  float lf = v - __uint_as_float(hb);
  unsigned ul = __float_as_uint(lf);
  h = (unsigned short)(hb >> 16);
  l = (unsigned short)((ul + 0x7FFFu + ((ul >> 16) & 1u)) >> 16);
}

// bf16 RNE of fp32
__device__ inline unsigned short bf16rne(float v) {
  unsigned u = __float_as_uint(v);
  return (unsigned short)((u + 0x7FFFu + ((u >> 16) & 1u)) >> 16);
}

// ---------------- prep: W-split (hi) + consts + E1/E2 tables + zero(cur) --------
__global__ __launch_bounds__(256) void k_prep(
    const float* __restrict__ Win, u16x8* __restrict__ Wf,
    const float* __restrict__ Wg1, const float* __restrict__ Wg2,
    const float* __restrict__ Wo, const float* __restrict__ bin,
    const float* __restrict__ bg1, const float* __restrict__ bg2,
    const float* __restrict__ bo, float4* __restrict__ E1,
    float2* __restrict__ E2, float* __restrict__ uv, int* __restrict__ cur) {
  __shared__ float wt[256][2];
  const int bid = blockIdx.x, tid = threadIdx.x;
  if (bid < 16) {
    // fragment f = nt*4 + ks (hi only); lane's 8 elems:
    //   Win[ks*32 + (lane>>4)*8 + j][nt*16 + (lane&15)]
    int f = bid * 4 + (tid >> 6);
    int lane = tid & 63;
    int nt = f >> 2, ks = f & 3;
    int n = nt * 16 + (lane & 15);
    int k0 = ks * 32 + (lane >> 4) * 8;
    u16x8 outv;
    #pragma unroll
    for (int j = 0; j < 8; ++j)
      outv[j] = bf16rne(Win[(size_t)(k0 + j) * HD + n]);
    Wf[f * 64 + lane] = outv;
  } else if (bid == 16) {
    int r = tid;
    float s0 = 0.f, s1 = 0.f;
    for (int k = 0; k < 256; ++k) {
      float w = Wg2[r * 256 + k];
      s0 = fmaf(w, Wo[k * 2 + 0], s0);
      s1 = fmaf(w, Wo[k * 2 + 1], s1);
    }
    wt[r][0] = s0; wt[r][1] = s1;
    __syncthreads();
    float b0 = 0.f, b1 = 0.f;
    for (int k = 0; k < 256; ++k) {
      float w = Wg1[r * 256 + k];
      b0 = fmaf(w, wt[k][0], b0);
      b1 = fmaf(w, wt[k][1], b1);
    }
    E1[r] = make_float4(bin[r], b0, b1, 0.f);          // {bias, wbig0, wbig1}
    E2[r] = make_float2(Wo[r * 2 + 0], Wo[r * 2 + 1]); // {wo0, wo1}
    if (r < 2) {
      float u = 0.f, v = 0.f;
      for (int k = 0; k < 256; ++k) {
        u = fmaf(bg1[k], wt[k][r], u);
        v = fmaf(bg2[k], Wo[k * 2 + r], v);
      }
      uv[r] = u;             // u[c]
      uv[2 + r] = v + bo[r]; // v[c]
    }
  } else {
    cur[tid] = 0;
  }
}

// ---------------- main: GEMM role [0,Gg) + edge-scatter role [Gg,Gg+NB) ---------
__global__ __launch_bounds__(256, 2) void k_main(
    const float* __restrict__ mf, const float* __restrict__ fe,
    const u16x8* __restrict__ Wf, const float4* __restrict__ E1,
    const float2* __restrict__ E2, const float* __restrict__ bo,
    float4* __restrict__ q, float* __restrict__ Pm,
    const int* __restrict__ src, const int* __restrict__ dst,
    int* __restrict__ cur, unsigned* __restrict__ packed,
    int N, int E, int Gg) {
  __shared__ __align__(16) char smem[20608];
  const int tid = threadIdx.x;
  const int lane = tid & 63, wid = tid >> 6;

  if ((int)blockIdx.x < Gg) {
    // ---- GEMM role: 4 waves x 16 rows = 64 rows/block ----
    float4* sE1 = (float4*)smem;           // 4 KB
    float2* sE2 = (float2*)(smem + 4096);  // 2 KB
    sE1[tid] = E1[tid];
    sE2[tid] = E2[tid];

    const int gb = blockIdx.x * 64;
    const int base = gb + wid * 16;
    int arow = base + (lane & 15);
    if (arow >= N) arow = N - 1;
    const int kb = (lane >> 4) * 8;
    const float* ap = mf + (size_t)arow * 128 + kb;
    const float* fp = fe + (size_t)arow * 128 + kb;

    // A fragments in regs: main = MF (hi/lo), mask = FE - MF (hi/lo)
    bf16x8 Ah[4], Al[4], Kh[4], Kl[4];
    #pragma unroll
    for (int ks = 0; ks < 4; ++ks) {
      float x[8], y[8];
      *(float4*)&x[0] = *(const float4*)(ap + ks * 32);
      *(float4*)&x[4] = *(const float4*)(ap + ks * 32 + 4);
      *(float4*)&y[0] = *(const float4*)(fp + ks * 32);
      *(float4*)&y[4] = *(const float4*)(fp + ks * 32 + 4);
      u16x8 hA, lA, hM, lM;
      #pragma unroll
      for (int j = 0; j < 8; ++j) {
        unsigned short hh, ll;
        split1(x[j], hh, ll);        hA[j] = hh; lA[j] = ll;
        split1(y[j] - x[j], hh, ll); hM[j] = hh; lM[j] = ll;
      }
      Ah[ks] = __builtin_bit_cast(bf16x8, hA);
      Al[ks] = __builtin_bit_cast(bf16x8, lA);
      Kh[ks] = __builtin_bit_cast(bf16x8, hM);
      Kl[ks] = __builtin_bit_cast(bf16x8, lM);
    }
    __syncthreads(); // sE1/sE2 ready

    const u16x8* wp = Wf + lane; // fragment stride = 64 lanes; 4 frags per nt
    float s0[4] = {}, s1[4] = {}, t0v[4] = {}, t1v[4] = {};
    u16x8 bA[4], bB[4];
    #pragma unroll
    for (int f = 0; f < 4; ++f) bA[f] = wp[f * 64]; // nt=0

    // 4 independent accumulator chains; B = hi only
    auto COMPUTE = [&](const u16x8* b, int nt) {
      f32x4 a0 = {0,0,0,0}, a1 = {0,0,0,0};
      f32x4 k0 = {0,0,0,0}, k1 = {0,0,0,0};
      #pragma unroll
      for (int ks = 0; ks < 4; ++ks) {
        bf16x8 bh = __builtin_bit_cast(bf16x8, b[ks]);
        a0 = MFMA16(Ah[ks], bh, a0, 0, 0, 0);
        a1 = MFMA16(Al[ks], bh, a1, 0, 0, 0);
        k0 = MFMA16(Kh[ks], bh, k0, 0, 0, 0);
        k1 = MFMA16(Kl[ks], bh, k1, 0, 0, 0);
      }
      const int col = nt * 16 + (lane & 15);
      const float4 e1 = sE1[col];
      const float2 e2 = sE2[col];
      #pragma unroll
      for (int r = 0; r < 4; ++r) {
        float a = (a0[r] + a1[r]) + e1.x;
        a = a > 0.f ? a : NEG_SLOPE * a;
        s0[r] = fmaf(a, e1.y, s0[r]); s1[r] = fmaf(a, e1.z, s1[r]);
        float m = (k0[r] + k1[r]) + e1.x;
        m = m > 0.f ? m : NEG_SLOPE * m;
        t0v[r] = fmaf(m, e2.x, t0v[r]); t1v[r] = fmaf(m, e2.y, t1v[r]);
      }
    };

    #pragma unroll 1
    for (int nt = 0; nt < 16; nt += 2) {
      #pragma unroll
      for (int f = 0; f < 4; ++f) bB[f] = wp[((nt + 1) * 4 + f) * 64];
      COMPUTE(bA, nt);
      if (nt + 2 < 16) {
        #pragma unroll
        for (int f = 0; f < 4; ++f) bA[f] = wp[((nt + 2) * 4 + f) * 64];
      }
      COMPUTE(bB, nt + 1);
    }

    #pragma unroll
    for (int o = 1; o < 16; o <<= 1) {
      #pragma unroll
      for (int r = 0; r < 4; ++r) {
        s0[r] += __shfl_xor(s0[r], o, 16);  s1[r] += __shfl_xor(s1[r], o, 16);
        t0v[r] += __shfl_xor(t0v[r], o, 16); t1v[r] += __shfl_xor(t1v[r], o, 16);
      }
    }
    if ((lane & 15) == 0) {
      float bo0 = bo[0], bo1 = bo[1];
      #pragma unroll
      for (int r = 0; r < 4; ++r) {
        int row = base + (lane >> 4) * 4 + r;
        if (row < N) {
          float* qf = (float*)&q[row];
          qf[1] = s0[r]; // P0 (unscaled); qf[0]=dis from k_p2
          qf[2] = s1[r]; // P1
          Pm[row * 2 + 0] = t0v[r] + bo0; // mask logit + b_out, final
          Pm[row * 2 + 1] = t1v[r] + bo1;
        }
      }
    }
    return;
  }

  // ---- scatter role: LDS hist+sort, coalesced per-bin global writes ----
  int* bins   = (int*)smem;              // 1 KB
  int* lstart = (int*)(smem + 1024);     // 1 KB
  int* gbase  = (int*)(smem + 2048);     // 1 KB
  int* lcur   = (int*)(smem + 3072);     // 1 KB
  int* wsum   = (int*)(smem + 4096);     // 16 B
  unsigned* sbuf = (unsigned*)(smem + 4112); // 16 KB
  const int t = tid, b = blockIdx.x - Gg;
  bins[t] = 0;
  __syncthreads();
  const int e0 = b * CHUNK, e1 = min(e0 + CHUNK, E), m = e1 - e0;
  for (int e = e0 + t; e < e1; e += 256)
    atomicAdd(&bins[dst[e] >> 8], 1);
  __syncthreads();
  {
    int v = bins[t], incl = v;
    #pragma unroll
    for (int o = 1; o < 64; o <<= 1) {
      int tmp = __shfl_up(incl, o, 64);
      if (lane >= o) incl += tmp;
    }
    if (lane == 63) wsum[wid] = incl;
    __syncthreads();
    int woff = 0;
    for (int w = 0; w < wid; ++w) woff += wsum[w];
    int st = woff + incl - v;
    lstart[t] = st;
    lcur[t] = st;
    gbase[t] = v ? atomicAdd(&cur[t], v) : 0;
  }
  __syncthreads();
  for (int e = e0 + t; e < e1; e += 256) {
    int d = dst[e], s = src[e];
    int slot = atomicAdd(&lcur[d >> 8], 1);
    sbuf[slot] = ((unsigned)d << 16) | (unsigned)s;
  }
  __syncthreads();
  for (int i = t; i < m; i += 256) {
    unsigned pv = sbuf[i];
    int bin = pv >> 24;
    packed[(size_t)bin * BSTRIDE + gbase[bin] + (i - lstart[bin])] = pv;
  }
}

// ---------------- p2: per-bucket sort -> rp/dis/csr ----------------
__global__ __launch_bounds__(256) void k_p2(
    const unsigned* __restrict__ packed, const int* __restrict__ cur,
    int* __restrict__ rp, float4* __restrict__ q, int* __restrict__ csr, int N) {
  __shared__ int cnt[256], sc[256];
  __shared__ int wsum[4];
  __shared__ unsigned short sbuf[BSTRIDE]; // 16 KB
  const int t = threadIdx.x;
  const int B = blockIdx.x;
  const int lane = t & 63, wid = t >> 6;
  int tot = cur[t], incl = tot;
  #pragma unroll
  for (int o = 1; o < 64; o <<= 1) {
    int tmp = __shfl_up(incl, o, 64);
    if (lane >= o) incl += tmp;
  }
  if (lane == 63) wsum[wid] = incl;
  __syncthreads();
  int woff = 0;
  for (int w = 0; w < wid; ++w) woff += wsum[w];
  sc[t] = woff + incl - tot;
  __syncthreads();
  const int base = sc[B];
  const int ecnt = cur[B];
  const unsigned* pk = packed + (size_t)B * BSTRIDE;
  cnt[t] = 0;
  __syncthreads();
  for (int i = t; i < ecnt; i += 256)
    atomicAdd(&cnt[(pk[i] >> 16) & 0xFF], 1);
  __syncthreads();
  int v = cnt[t];
  incl = v;
  #pragma unroll
  for (int o = 1; o < 64; o <<= 1) {
    int tmp = __shfl_up(incl, o, 64);
    if (lane >= o) incl += tmp;
  }
  if (lane == 63) wsum[wid] = incl;
  __syncthreads();
  woff = 0;
  for (int w = 0; w < wid; ++w) woff += wsum[w];
  const int off = woff + incl - v;
  const int node = B * 256 + t;
  if (node < N) {
    rp[node] = base + off;
    ((float*)&q[node])[0] = rsqrtf((float)(v + 1)); // dis (+1 self-loop)
  } else if (node == N) {
    rp[N] = base + off; // == E
  }
  __syncthreads();
  cnt[t] = off; // LDS cursor
  __syncthreads();
  for (int i = t; i < ecnt; i += 256) {
    unsigned pv = pk[i];
    int slot = atomicAdd(&cnt[(pv >> 16) & 0xFF], 1);
    sbuf[slot] = (unsigned short)(pv & 0xFFFFu);
  }
  __syncthreads();
  for (int i = t; i < ecnt; i += 256)
    csr[base + i] = (int)sbuf[i];
}

// ---------------- gather passes (8 lanes/node, 2x unroll) ----------------
// q[n] = {dis, P0, P1, -};  T2[n] = dis[n]*(dis[n]*(dis[n]*P[n] + sum dis[s]P[s]) + u)
__global__ __launch_bounds__(256) void k_gather1(
    const int* __restrict__ rp, const int* __restrict__ csr,
    const float4* __restrict__ q, const float* __restrict__ uv,
    float* __restrict__ T2, int N) {
  int t = threadIdx.x;
  int n = blockIdx.x * 32 + (t >> 3);
  int l = t & 7;
  if (n >= N) return;
  int s0 = rp[n], s1 = rp[n + 1];
  float a0 = 0.f, a1 = 0.f;
  int j = s0 + l;
  for (; j + 8 < s1; j += 16) {
    int i0 = csr[j], i1 = csr[j + 8];
    float4 q0 = q[i0], q1 = q[i1];
    a0 = fmaf(q0.x, q0.y, a0); a1 = fmaf(q0.x, q0.z, a1);
    a0 = fmaf(q1.x, q1.y, a0); a1 = fmaf(q1.x, q1.z, a1);
  }
  if (j < s1) {
    float4 qa = q[csr[j]];
    a0 = fmaf(qa.x, qa.y, a0); a1 = fmaf(qa.x, qa.z, a1);
  }
  a0 += __shfl_xor(a0, 1, 8); a1 += __shfl_xor(a1, 1, 8);
  a0 += __shfl_xor(a0, 2, 8); a1 += __shfl_xor(a1, 2, 8);
  a0 += __shfl_xor(a0, 4, 8); a1 += __shfl_xor(a1, 4, 8);
  if (l == 0) {
    float4 qn = q[n];
    float d = qn.x;
    T2[n * 2 + 0] = d * (d * fmaf(d, qn.y, a0) + uv[0]);
    T2[n * 2 + 1] = d * (d * fmaf(d, qn.z, a1) + uv[1]);
  }
}

// out[n] = (dis[n]*(T2[n] + sum T2[s]) + v) * Pm[n]   (Pm already has +b_out)
__global__ __launch_bounds__(256) void k_gather2(
    const int* __restrict__ rp, const int* __restrict__ csr,
    const float* __restrict__ T2, const float4* __restrict__ q,
    const float* __restrict__ uv, const float* __restrict__ Pm,
    float* __restrict__ out, int N) {
  int t = threadIdx.x;
  int n = blockIdx.x * 32 + (t >> 3);
  int l = t & 7;
  if (n >= N) return;
  int s0 = rp[n], s1 = rp[n + 1];
  float a0 = 0.f, a1 = 0.f;
  int j = s0 + l;
  for (; j + 8 < s1; j += 16) {
    int i0 = csr[j], i1 = csr[j + 8];
    float2 v0 = *(const float2*)&T2[i0 * 2];
    float2 v1 = *(const float2*)&T2[i1 * 2];
    a0 += v0.x + v1.x; a1 += v0.y + v1.y;
  }
  if (j < s1) {
    float2 va = *(const float2*)&T2[csr[j] * 2];
    a0 += va.x; a1 += va.y;
  }
  a0 += __shfl_xor(a0, 1, 8); a1 += __shfl_xor(a1, 1, 8);
  a0 += __shfl_xor(a0, 2, 8); a1 += __shfl_xor(a1, 2, 8);
  a0 += __shfl_xor(a0, 4, 8); a1 += __shfl_xor(a1, 4, 8);
  if (l == 0) {
    float d = q[n].x;
    float2 tv = *(const float2*)&T2[n * 2];
    float z0 = d * (tv.x + a0) + uv[2];
    float z1 = d * (tv.y + a1) + uv[3];
    out[n * 2 + 0] = z0 * Pm[n * 2 + 0];
    out[n * 2 + 1] = z1 * Pm[n * 2 + 1];
  }
}

extern "C" void kernel_launch(void* const* d_in, const int* in_sizes, int n_in,
                              void* d_out, int out_size, void* d_ws, size_t ws_size,
                              hipStream_t stream) {
  const float* mf  = (const float*)d_in[0];
  const float* fe  = (const float*)d_in[1];
  const int*   ei  = (const int*)d_in[2];
  const float* Win = (const float*)d_in[4];
  const float* bin = (const float*)d_in[5];
  const float* Wg1 = (const float*)d_in[6];
  const float* bg1 = (const float*)d_in[7];
  const float* Wg2 = (const float*)d_in[8];
  const float* bg2 = (const float*)d_in[9];
  const float* Wo  = (const float*)d_in[10];
  const float* bo  = (const float*)d_in[11];
  float* out = (float*)d_out;

  const int ED = 128;
  const int N = in_sizes[0] / ED;  // 50000
  const int E = in_sizes[3];       // 800000
  const int* src = ei;
  const int* dst = ei + E;

  char* ws = (char*)d_ws;
  size_t off = 0;
  auto carve = [&](size_t bytes) {
    char* p = ws + off;
    off += (bytes + 255) & ~(size_t)255;
    return p;
  };
  int*      cur    = (int*)carve(256 * 4);
  unsigned* packed = (unsigned*)carve((size_t)256 * BSTRIDE * 4); // 8 MB
  int*      csr    = (int*)carve((size_t)E * 4);
  int*      rp     = (int*)carve((size_t)(N + 1) * 4);
  float4*   q      = (float4*)carve((size_t)N * 16);   // {dis, P0, P1, -}
  float*    T2     = (float*)carve((size_t)N * 2 * 4);
  float*    Pm     = (float*)carve((size_t)N * 2 * 4);
  float4*   E1     = (float4*)carve((size_t)HD * 16);  // {bias, wbig0, wbig1, -}
  float2*   E2     = (float2*)carve((size_t)HD * 8);   // {wo0, wo1}
  float*    uv     = (float*)carve(4 * 4);
  u16x8*    Wf     = (u16x8*)carve((size_t)64 * 64 * 16); // 64 KB (hi only)
  (void)ws_size; (void)n_in; (void)out_size;

  const int NB  = (E + CHUNK - 1) / CHUNK;  // 196 scatter role blocks
  const int NP2 = (N + 255) / 256;          // 196 buckets
  const int Gg  = (N + 63) / 64;            // 782 GEMM role blocks
  const int Gt  = (N + 31) / 32;            // 1563 gather blocks

  k_prep<<<18, 256, 0, stream>>>(Win, Wf, Wg1, Wg2, Wo, bin, bg1, bg2, bo,
                                 E1, E2, uv, cur);
  k_main<<<Gg + NB, 256, 0, stream>>>(mf, fe, Wf, E1, E2, bo, q, Pm,
                                      src, dst, cur, packed, N, E, Gg);
  k_p2<<<NP2, 256, 0, stream>>>(packed, cur, rp, q, csr, N);
  k_gather1<<<Gt, 256, 0, stream>>>(rp, csr, q, uv, T2, N);
  k_gather2<<<Gt, 256, 0, stream>>>(rp, csr, T2, q, uv, Pm, out, N);
}